// Round 1
// baseline (187.582 us; speedup 1.0000x reference)
//
#include <hip/hip_runtime.h>
#include <math.h>

// Problem constants (fixed dataset: query [65536,512] f32, protos [64,512] f32, k=3)
#define DIM     512
#define NPROTO  64
#define TILE_R  64          // rows per block
#define BK      64          // K-chunk
#define LS      68          // LDS row stride (floats), mult of 4 for b128 align, breaks pow2 banks
#define SIMS    65          // sim row stride (doubles)

// ---------------------------------------------------------------------------
// Kernel 1: fp64-normalize prototypes, store transposed protoT[k][p] (fp32).
// One wave per prototype.
// ---------------------------------------------------------------------------
__global__ __launch_bounds__(256) void prep_protos_kernel(
    const float* __restrict__ protos, float* __restrict__ protoT) {
  const int p = (blockIdx.x * blockDim.x + threadIdx.x) >> 6;
  const int lane = threadIdx.x & 63;
  if (p >= NPROTO) return;
  const float4* pr = (const float4*)(protos + (size_t)p * DIM);
  const float4 a = pr[lane * 2];
  const float4 b = pr[lane * 2 + 1];
  double ss = (double)a.x * a.x + (double)a.y * a.y + (double)a.z * a.z +
              (double)a.w * a.w + (double)b.x * b.x + (double)b.y * b.y +
              (double)b.z * b.z + (double)b.w * b.w;
#pragma unroll
  for (int m = 1; m < 64; m <<= 1) ss += __shfl_xor(ss, m);
  const double inv = 1.0 / fmax(sqrt(ss), 1e-12);
  const float v[8] = {a.x, a.y, a.z, a.w, b.x, b.y, b.z, b.w};
#pragma unroll
  for (int e = 0; e < 8; ++e)
    protoT[(size_t)(lane * 8 + e) * NPROTO + p] = (float)((double)v[e] * inv);
}

// ---------------------------------------------------------------------------
// Kernel 2: fused  sim-GEMM (fp64 acc) -> top3 -> softmax -> weighted gather.
// Block = 256 threads = 4 waves; handles 64 query rows.
// ---------------------------------------------------------------------------
__global__ __launch_bounds__(256) void proto_bank_kernel(
    const float* __restrict__ query, const float* __restrict__ protos,
    const float* __restrict__ protoT, float* __restrict__ out) {
  __shared__ float AB[2 * BK * LS];   // As | Bs ; reused as simS (doubles) after GEMM
  __shared__ double qinvS[TILE_R];
  __shared__ int   topiS[TILE_R][3];
  __shared__ float topwS[TILE_R][3];

  const int t = threadIdx.x;
  const int row0 = blockIdx.x * TILE_R;
  const int tr = t >> 4;     // 0..15 -> rows 4*tr..4*tr+3
  const int tp = t & 15;     // 0..15 -> protos 4*tp..4*tp+3
  const int srow = t >> 2;   // 0..63 staging row
  const int sq = t & 3;      // staging quarter (16 floats)

  float* As = AB;
  float* Bs = AB + BK * LS;

  double acc[4][4] = {{0.0, 0.0, 0.0, 0.0},
                      {0.0, 0.0, 0.0, 0.0},
                      {0.0, 0.0, 0.0, 0.0},
                      {0.0, 0.0, 0.0, 0.0}};
  double ss = 0.0;  // per-thread partial sumsq of its quarter of query row `srow`

  const float* qsrc = query + (size_t)(row0 + srow) * DIM + sq * 16;
  const float* bsrc = protoT + (size_t)srow * NPROTO + sq * 16;

  for (int ks = 0; ks < DIM / BK; ++ks) {
    const int k0 = ks * BK;
    float4 av[4], bv[4];
    const float4* qp = (const float4*)(qsrc + k0);
    const float4* bp = (const float4*)(bsrc + (size_t)k0 * NPROTO);
#pragma unroll
    for (int i = 0; i < 4; ++i) av[i] = qp[i];
#pragma unroll
    for (int i = 0; i < 4; ++i) bv[i] = bp[i];
#pragma unroll
    for (int i = 0; i < 4; ++i) {
      ss += (double)av[i].x * av[i].x + (double)av[i].y * av[i].y +
            (double)av[i].z * av[i].z + (double)av[i].w * av[i].w;
    }
    __syncthreads();  // previous iteration's LDS reads complete
    // A staged transposed: As[kk][row]
#pragma unroll
    for (int i = 0; i < 4; ++i) {
      const float va[4] = {av[i].x, av[i].y, av[i].z, av[i].w};
#pragma unroll
      for (int e = 0; e < 4; ++e)
        As[(sq * 16 + i * 4 + e) * LS + srow] = va[e];
    }
    // B staged row-contiguous: Bs[kk][proto]
#pragma unroll
    for (int i = 0; i < 4; ++i)
      *(float4*)&Bs[srow * LS + sq * 16 + i * 4] = bv[i];
    __syncthreads();

#pragma unroll 4
    for (int kk = 0; kk < BK; ++kk) {
      const float4 a4 = *(const float4*)&As[kk * LS + tr * 4];
      const float4 b4 = *(const float4*)&Bs[kk * LS + tp * 4];
      const double ad[4] = {a4.x, a4.y, a4.z, a4.w};
      const double bd[4] = {b4.x, b4.y, b4.z, b4.w};
#pragma unroll
      for (int i = 0; i < 4; ++i)
#pragma unroll
        for (int j = 0; j < 4; ++j) acc[i][j] = fma(ad[i], bd[j], acc[i][j]);
    }
  }

  // combine quarter-row sumsq (4 consecutive lanes per row)
  ss += __shfl_xor(ss, 1);
  ss += __shfl_xor(ss, 2);
  if (sq == 0) qinvS[srow] = 1.0 / fmax(sqrt(ss), 1e-12);
  __syncthreads();  // all GEMM LDS reads done; qinvS visible

  // write scaled sims into reused LDS (fp64): sim = (q . pn) / |q|
  double* simS = (double*)AB;  // 64 * 65 * 8 = 33280 B <= 34816 B
#pragma unroll
  for (int i = 0; i < 4; ++i) {
    const double qi = qinvS[tr * 4 + i];
#pragma unroll
    for (int j = 0; j < 4; ++j)
      simS[(size_t)(tr * 4 + i) * SIMS + tp * 4 + j] = acc[i][j] * qi;
  }
  __syncthreads();

  // top-3 per row (thread t scans row t), softmax in fp32
  if (t < TILE_R) {
    const double* sr = simS + (size_t)t * SIMS;
    double v1 = -1e300, v2 = -1e300, v3 = -1e300;
    int i1 = 0, i2 = 0, i3 = 0;
    for (int j = 0; j < NPROTO; ++j) {
      const double v = sr[j];
      if (v > v1) {
        v3 = v2; i3 = i2; v2 = v1; i2 = i1; v1 = v; i1 = j;
      } else if (v > v2) {
        v3 = v2; i3 = i2; v2 = v; i2 = j;
      } else if (v > v3) {
        v3 = v; i3 = j;
      }
    }
    const float e2 = expf((float)(v2 - v1));
    const float e3 = expf((float)(v3 - v1));
    const float invsum = 1.0f / (1.0f + e2 + e3);
    topiS[t][0] = i1; topiS[t][1] = i2; topiS[t][2] = i3;
    topwS[t][0] = invsum; topwS[t][1] = e2 * invsum; topwS[t][2] = e3 * invsum;
  }
  __syncthreads();

  // output: wave w writes rows 16w..16w+15; lane covers 8 floats (2x float4)
  const int w = t >> 6;
  const int lane = t & 63;
#pragma unroll
  for (int r = 0; r < 16; ++r) {
    const int row = w * 16 + r;
    const int i0 = topiS[row][0], i1 = topiS[row][1], i2 = topiS[row][2];
    const float w0 = topwS[row][0], w1 = topwS[row][1], w2 = topwS[row][2];
    const float4* p0 = (const float4*)(protos + (size_t)i0 * DIM) + lane * 2;
    const float4* p1 = (const float4*)(protos + (size_t)i1 * DIM) + lane * 2;
    const float4* p2 = (const float4*)(protos + (size_t)i2 * DIM) + lane * 2;
    float4* o = (float4*)(out + (size_t)(row0 + row) * DIM) + lane * 2;
#pragma unroll
    for (int u = 0; u < 2; ++u) {
      const float4 a = p0[u], b = p1[u], c = p2[u];
      float4 res;
      res.x = w0 * a.x + w1 * b.x + w2 * c.x;
      res.y = w0 * a.y + w1 * b.y + w2 * c.y;
      res.z = w0 * a.z + w1 * b.z + w2 * c.z;
      res.w = w0 * a.w + w1 * b.w + w2 * c.w;
      o[u] = res;
    }
  }
}

extern "C" void kernel_launch(void* const* d_in, const int* in_sizes, int n_in,
                              void* d_out, int out_size, void* d_ws, size_t ws_size,
                              hipStream_t stream) {
  const float* query = (const float*)d_in[0];
  const float* protos = (const float*)d_in[1];
  float* out = (float*)d_out;
  float* protoT = (float*)d_ws;  // 512*64 floats = 128 KiB scratch

  const int nrows = in_sizes[0] / DIM;

  hipLaunchKernelGGL(prep_protos_kernel, dim3(16), dim3(256), 0, stream,
                     protos, protoT);
  hipLaunchKernelGGL(proto_bank_kernel, dim3(nrows / TILE_R), dim3(256), 0,
                     stream, query, protos, protoT, out);
}